// Round 7
// baseline (220.782 us; speedup 1.0000x reference)
//
#include <hip/hip_runtime.h>

#define SEQ   2048
#define CZ    64
#define VBINS (2 * (SEQ - 1) + 1)   // 4095

typedef float f32x4 __attribute__((ext_vector_type(4)));

// ---------------------------------------------------------------------------
// Pass 1: T[r][c] = W[c][r] + bias[c]   (transposed, bias-fused table)
// T is VBINS x CZ f32 ~= 1 MiB. Negligible cost; W is L2-resident.
// ---------------------------------------------------------------------------
__global__ void build_table_kernel(const float* __restrict__ W,
                                   const float* __restrict__ bias,
                                   float* __restrict__ T) {
    int idx = blockIdx.x * blockDim.x + threadIdx.x;   // over r*CZ + c
    const int total = VBINS * CZ;
    if (idx < total) {
        int r = idx >> 6;       // idx / CZ
        int c = idx & 63;       // idx % CZ
        T[idx] = W[c * VBINS + r] + bias[c];
    }
}

// ---------------------------------------------------------------------------
// Pass 2: out[i, :, :] = T_flat[RI[i,0]*CZ : RI[i,0]*CZ + SEQ*CZ]
// Row-grouped copy: one block handles G=4 CONSECUTIVE rows. rbase(i)=2047-i,
// so the 4 rows' table slices overlap 2047/2048. Chunk-major order (chunk c
// of row 0,1,2,3 back-to-back) re-reads each 128 KiB chunk 3x within
// microseconds -> L2-hits before the write stream can evict -> aggregate
// read-fabric traffic drops ~4x (1 GiB -> ~270 MiB), freeing the XCD<->MALL
// path for write evictions.
// 512 blocks x 1024 threads = 2 blocks/CU = 32 waves/CU (MLP unchanged).
// Plain cached stores (NT measured worse). U=8, VGPR ~56 <= 64.
// ---------------------------------------------------------------------------
__global__ void __launch_bounds__(1024, 8)
copy_rows_kernel(const int* __restrict__ RI,
                 const float* __restrict__ T,
                 float* __restrict__ out) {
    constexpr int THREADS = 1024;
    constexpr int U       = 8;
    constexpr int CHUNK   = U * THREADS;           // 8192 float4 = 128 KiB
    constexpr int N       = SEQ * CZ / 4;          // 32768 float4 per row
    constexpr int NIT     = N / CHUNK;             // 4 chunks per row
    constexpr int G       = 4;                     // rows per block

    const int blk = blockIdx.x;                    // 0..511
    const int i0  = blk * G;
    const int tid = threadIdx.x;

    // Per-row bases (uniform scalar loads).
    const f32x4* src[G];
    f32x4*       dst[G];
    #pragma unroll
    for (int g = 0; g < G; ++g) {
        const int i = i0 + g;
        const int rbase = RI[(long long)i << 11];  // RI[i][0]
        src[g] = reinterpret_cast<const f32x4*>(T) + ((long long)rbase << 4);
        dst[g] = reinterpret_cast<f32x4*>(out)     + ((long long)i << 15);
    }

    // Chunk-major: same 128 KiB table window re-used G times back-to-back.
    for (int it = 0; it < NIT; ++it) {
        const int base = it * CHUNK + tid;
        #pragma unroll
        for (int g = 0; g < G; ++g) {
            f32x4 a[U];
            #pragma unroll
            for (int u = 0; u < U; ++u) a[u] = src[g][base + u * THREADS];
            #pragma unroll
            for (int u = 0; u < U; ++u) dst[g][base + u * THREADS] = a[u];
        }
    }
}

// ---------------------------------------------------------------------------
// Fallback (if d_ws too small for the 1 MiB table): per-element gather from W
// with inline bias add.
// ---------------------------------------------------------------------------
__global__ void gather_direct_kernel(const int* __restrict__ RI,
                                     const float* __restrict__ W,
                                     const float* __restrict__ bias,
                                     float* __restrict__ out) {
    const long long total = (long long)SEQ * SEQ * (CZ / 4);
    const long long stride = (long long)gridDim.x * blockDim.x;
    long long idx = (long long)blockIdx.x * blockDim.x + threadIdx.x;
    for (; idx < total; idx += stride) {
        int ij = (int)(idx >> 4);
        int q  = (int)(idx & 15);
        int r  = RI[ij];
        int c0 = q << 2;
        f32x4 v;
        v.x = W[(c0 + 0) * VBINS + r] + bias[c0 + 0];
        v.y = W[(c0 + 1) * VBINS + r] + bias[c0 + 1];
        v.z = W[(c0 + 2) * VBINS + r] + bias[c0 + 2];
        v.w = W[(c0 + 3) * VBINS + r] + bias[c0 + 3];
        reinterpret_cast<f32x4*>(out)[idx] = v;
    }
}

extern "C" void kernel_launch(void* const* d_in, const int* in_sizes, int n_in,
                              void* d_out, int out_size, void* d_ws, size_t ws_size,
                              hipStream_t stream) {
    const int*   RI   = (const int*)d_in[0];     // (SEQ, SEQ) int32
    const float* W    = (const float*)d_in[1];   // (CZ, VBINS) f32
    const float* bias = (const float*)d_in[2];   // (CZ,) f32
    float*       out  = (float*)d_out;           // (SEQ, SEQ, CZ) f32

    const size_t table_bytes = (size_t)VBINS * CZ * sizeof(float);

    if (ws_size >= table_bytes) {
        float* T = (float*)d_ws;
        const int total1 = VBINS * CZ;
        build_table_kernel<<<(total1 + 255) / 256, 256, 0, stream>>>(W, bias, T);
        copy_rows_kernel<<<SEQ / 4, 1024, 0, stream>>>(RI, T, out);  // 4 rows/block
    } else {
        gather_direct_kernel<<<2048, 256, 0, stream>>>(RI, W, bias, out);
    }
}

// Round 8
// 192.867 us; speedup vs baseline: 1.1447x; 1.1447x over previous
//
#include <hip/hip_runtime.h>

#define SEQ   2048
#define CZ    64
#define VBINS (2 * (SEQ - 1) + 1)   // 4095

typedef float f32x4 __attribute__((ext_vector_type(4)));

// ---------------------------------------------------------------------------
// Pass 1: T[r][c] = W[c][r] + bias[c]   (transposed, bias-fused table)
// T is VBINS x CZ f32 ~= 1 MiB. Negligible cost; W is L2-resident.
// ---------------------------------------------------------------------------
__global__ void build_table_kernel(const float* __restrict__ W,
                                   const float* __restrict__ bias,
                                   float* __restrict__ T) {
    int idx = blockIdx.x * blockDim.x + threadIdx.x;   // over r*CZ + c
    const int total = VBINS * CZ;
    if (idx < total) {
        int r = idx >> 6;       // idx / CZ
        int c = idx & 63;       // idx % CZ
        T[idx] = W[c * VBINS + r] + bias[c];
    }
}

// ---------------------------------------------------------------------------
// Pass 2: out[i, :, :] = T_flat[RI[i,0]*CZ : RI[i,0]*CZ + SEQ*CZ]
// Best measured config (R6, 192.9 us): one 256-thread block per row,
// U=8 single-buffered (8 float4 loads in flight -> one implicit waitcnt ->
// 8 plain cached float4 stores), 16 iterations per row.
// A/B history: NT stores -10 us worse (R4->R5); U=4 ping-pong -3 us worse
// (R5->R6); 4-row grouping +28 us worse (R7). Write-throughput-bound at
// ~90% of the chip's pure-fill write rate.
// ---------------------------------------------------------------------------
__global__ void __launch_bounds__(256, 8)
copy_rows_kernel(const int* __restrict__ RI,
                 const float* __restrict__ T,
                 float* __restrict__ out) {
    const int i = blockIdx.x;                      // output row
    const int rbase = RI[(long long)i << 11];      // RI[i][0]  (uniform)
    const f32x4* __restrict__ src = reinterpret_cast<const f32x4*>(T) + ((long long)rbase << 4);
    f32x4* __restrict__ dst       = reinterpret_cast<f32x4*>(out)     + ((long long)i << 15);

    constexpr int THREADS = 256;
    constexpr int U       = 8;                     // float4 per phase per thread
    constexpr int CHUNK   = U * THREADS;           // 2048 float4 per phase
    constexpr int N       = SEQ * CZ / 4;          // 32768 float4 per row
    constexpr int NIT     = N / CHUNK;             // 16 phases

    const int tid = threadIdx.x;
    f32x4 a[U];

    for (int it = 0; it < NIT; ++it) {
        const int base = it * CHUNK + tid;
        #pragma unroll
        for (int u = 0; u < U; ++u) a[u] = src[base + u * THREADS];
        #pragma unroll
        for (int u = 0; u < U; ++u) dst[base + u * THREADS] = a[u];
    }
}

// ---------------------------------------------------------------------------
// Fallback (if d_ws too small for the 1 MiB table): per-element gather from W
// with inline bias add.
// ---------------------------------------------------------------------------
__global__ void gather_direct_kernel(const int* __restrict__ RI,
                                     const float* __restrict__ W,
                                     const float* __restrict__ bias,
                                     float* __restrict__ out) {
    const long long total = (long long)SEQ * SEQ * (CZ / 4);
    const long long stride = (long long)gridDim.x * blockDim.x;
    long long idx = (long long)blockIdx.x * blockDim.x + threadIdx.x;
    for (; idx < total; idx += stride) {
        int ij = (int)(idx >> 4);
        int q  = (int)(idx & 15);
        int r  = RI[ij];
        int c0 = q << 2;
        f32x4 v;
        v.x = W[(c0 + 0) * VBINS + r] + bias[c0 + 0];
        v.y = W[(c0 + 1) * VBINS + r] + bias[c0 + 1];
        v.z = W[(c0 + 2) * VBINS + r] + bias[c0 + 2];
        v.w = W[(c0 + 3) * VBINS + r] + bias[c0 + 3];
        reinterpret_cast<f32x4*>(out)[idx] = v;
    }
}

extern "C" void kernel_launch(void* const* d_in, const int* in_sizes, int n_in,
                              void* d_out, int out_size, void* d_ws, size_t ws_size,
                              hipStream_t stream) {
    const int*   RI   = (const int*)d_in[0];     // (SEQ, SEQ) int32
    const float* W    = (const float*)d_in[1];   // (CZ, VBINS) f32
    const float* bias = (const float*)d_in[2];   // (CZ,) f32
    float*       out  = (float*)d_out;           // (SEQ, SEQ, CZ) f32

    const size_t table_bytes = (size_t)VBINS * CZ * sizeof(float);
    const int block = 256;

    if (ws_size >= table_bytes) {
        float* T = (float*)d_ws;
        const int total1 = VBINS * CZ;
        build_table_kernel<<<(total1 + block - 1) / block, block, 0, stream>>>(W, bias, T);
        copy_rows_kernel<<<SEQ, block, 0, stream>>>(RI, T, out);   // 1 block per row
    } else {
        gather_direct_kernel<<<2048, block, 0, stream>>>(RI, W, bias, out);
    }
}